// Round 1
// baseline (339.063 us; speedup 1.0000x reference)
//
#include <hip/hip_runtime.h>
#include <cstdint>
#include <cstddef>

// Problem constants (from reference setup_inputs)
#define BB 64
#define TT 256
#define DD 512
#define BK 32
#define TILEM 128

typedef short bf16x8 __attribute__((ext_vector_type(8)));  // 8 bf16 in 4 VGPRs
typedef float f32x4  __attribute__((ext_vector_type(4)));  // MFMA acc
typedef int   i32x4  __attribute__((ext_vector_type(4)));  // 16B LDS store

// fp32 -> bf16, round-half-up (1 add + shift; bias 2^-17, irrelevant vs threshold)
static __device__ __forceinline__ unsigned short f2bf(float x) {
  unsigned u = __builtin_bit_cast(unsigned, x) + 0x8000u;
  return (unsigned short)(u >> 16);
}

// SYMMETRY: out_r[b] = sum_t w (r r^T + i i^T) is symmetric; out_i antisymmetric.
// So only the 10 lower-triangular 128x128 tiles per batch are computed (vs 16):
// -37.5% MFMA work and staged-read traffic. Off-diagonal blocks write their tile
// AND the mirrored tile (out_r copied, out_i negated), transposed through LDS so
// the mirrored stores stay coalesced.
//
// Grid: 640 blocks = 8 XCD clusters x 8 batches x 10 triangular tiles.
// c = L%8 is the XCD (hardware round-robin of linear workgroup id), so each
// XCD keeps 8 batches' inputs hot in its private L2.
//
// All output stores are NON-TEMPORAL: 131 MB of streamed output must not evict
// the reusable input panels from the 4 MiB/XCD L2.
__global__ __launch_bounds__(256, 2)
void ComplexMixture_54838142435828_kernel(const float* __restrict__ re,
                                          const float* __restrict__ im,
                                          const float* __restrict__ wt,
                                          float* __restrict__ out) {
  // Unified LDS: staging arrays during k-loop; first 32 KB reused by the
  // epilogue transpose (8 KB per wave).
  __shared__ __attribute__((aligned(16))) char smem[33792];
  unsigned short* sAr = (unsigned short*)(smem);           // w*R, rows d   (8 KB)
  unsigned short* sAi = (unsigned short*)(smem + 8192);    // w*I, rows d   (8 KB)
  unsigned short* sBr = (unsigned short*)(smem + 16384);   // R, cols e     (8 KB)
  unsigned short* sBi = (unsigned short*)(smem + 24576);   // I, cols e     (8 KB)
  float*          sw  = (float*)(smem + 32768);            // weights       (1 KB)

  const int tid = threadIdx.x;

  // ---- XCD-cluster swizzle + triangular tile map ----
  const int L = blockIdx.x;        // 0..639
  const int c = L & 7;             // XCD (round-robin dispatch by linear id)
  const int s = L >> 3;            // 0..79 within XCD
  const int b  = c * 8 + s / 10;   // 8 batches per XCD, 10 tiles each
  const int t  = s % 10;           // triangular tile id 0..9
  const int ti = (t >= 6) ? 3 : (t >= 3) ? 2 : (t >= 1) ? 1 : 0;
  const int tj = t - ((ti * (ti + 1)) >> 1);   // ti >= tj always
  const int d0 = ti * TILEM;       // output row tile
  const int e0 = tj * TILEM;       // output col tile

  sw[tid] = wt[b * TT + tid];  // T == blockDim.x == 256; synced by loop-top barrier

  const int lane = tid & 63;
  const int wid  = tid >> 6;
  const int wm = (wid >> 1) * 64;  // wave row offset in tile
  const int wn = (wid & 1) * 64;   // wave col offset in tile
  const int quad = lane >> 4;      // selects k-octet (chunk)
  const int l16  = lane & 15;

  f32x4 accR[4][4], accI[4][4];
  #pragma unroll
  for (int mt = 0; mt < 4; ++mt)
    #pragma unroll
    for (int nt = 0; nt < 4; ++nt) {
      accR[mt][nt] = (f32x4){0.f, 0.f, 0.f, 0.f};
      accI[mt][nt] = (f32x4){0.f, 0.f, 0.f, 0.f};
    }

  // Staging role: thread covers column (d0|e0)+sd, k-range [kh*16, kh*16+16)
  const int sd = tid & 127;
  const int kh = tid >> 7;

  for (int kt = 0; kt < TT; kt += BK) {
    __syncthreads();  // protect LDS from previous iteration's readers (and sw init)

    // ---------------- stage global -> LDS (transpose to k-contiguous, bf16) ---------
    const int kb = kt + kh * 16;  // global t base for this thread (within [0,T))
    const size_t rowBase = ((size_t)(b * TT + kb)) * DD;

    {  // A-side tiles (w-scaled), columns d0..d0+127
      const float* pr = re + rowBase + d0 + sd;
      const float* pi = im + rowBase + d0 + sd;
      #pragma unroll
      for (int cc = 0; cc < 2; ++cc) {
        union { unsigned short h[8]; i32x4 q; } ur, ui;
        #pragma unroll
        for (int j = 0; j < 8; ++j) {
          const int k = cc * 8 + j;
          const float wv = sw[kb + k];
          ur.h[j] = f2bf(pr[(size_t)k * DD] * wv);
          ui.h[j] = f2bf(pi[(size_t)k * DD] * wv);
        }
        const int off = ((kh * 2 + cc) * 128 + sd) * 8;
        *(i32x4*)&sAr[off] = ur.q;
        *(i32x4*)&sAi[off] = ui.q;
      }
    }
    {  // B-side tiles (unscaled), columns e0..e0+127
      const float* qr = re + rowBase + e0 + sd;
      const float* qi = im + rowBase + e0 + sd;
      #pragma unroll
      for (int cc = 0; cc < 2; ++cc) {
        union { unsigned short h[8]; i32x4 q; } ur, ui;
        #pragma unroll
        for (int j = 0; j < 8; ++j) {
          const int k = cc * 8 + j;
          ur.h[j] = f2bf(qr[(size_t)k * DD]);
          ui.h[j] = f2bf(qi[(size_t)k * DD]);
        }
        const int off = ((kh * 2 + cc) * 128 + sd) * 8;
        *(i32x4*)&sBr[off] = ur.q;
        *(i32x4*)&sBi[off] = ui.q;
      }
    }
    __syncthreads();

    // ---------------- compute: one MFMA K=32 step ----------------------------------
    // A frag: A[m=lane&15][k=quad*8+j]  (m89-verified); B symmetric.
    bf16x8 aR[4], aI[4], bR[4], bI[4];
    #pragma unroll
    for (int tt = 0; tt < 4; ++tt) {
      const int offA = (quad * 128 + wm + tt * 16 + l16) * 8;
      const int offB = (quad * 128 + wn + tt * 16 + l16) * 8;
      aR[tt] = *(const bf16x8*)&sAr[offA];
      aI[tt] = *(const bf16x8*)&sAi[offA];
      bR[tt] = *(const bf16x8*)&sBr[offB];
      bI[tt] = *(const bf16x8*)&sBi[offB];
    }
    #pragma unroll
    for (int mt = 0; mt < 4; ++mt) {
      const bf16x8 aRn = aR[mt] ^ (bf16x8)((short)0x8000);  // -(w*R) via sign flip
      #pragma unroll
      for (int nt = 0; nt < 4; ++nt) {
        accR[mt][nt] = __builtin_amdgcn_mfma_f32_16x16x32_bf16(aR[mt], bR[nt], accR[mt][nt], 0, 0, 0);
        accR[mt][nt] = __builtin_amdgcn_mfma_f32_16x16x32_bf16(aI[mt], bI[nt], accR[mt][nt], 0, 0, 0);
        accI[mt][nt] = __builtin_amdgcn_mfma_f32_16x16x32_bf16(aI[mt], bR[nt], accI[mt][nt], 0, 0, 0);
        accI[mt][nt] = __builtin_amdgcn_mfma_f32_16x16x32_bf16(aRn,    bI[nt], accI[mt][nt], 0, 0, 0);
      }
    }
  }

  // ---------------- epilogue 1: direct tile (C/D layout col=lane&15, row=quad*4+r) --
  const size_t NOFF = (size_t)BB * DD * DD;  // out_i offset in flat tuple output
  #pragma unroll
  for (int mt = 0; mt < 4; ++mt) {
    #pragma unroll
    for (int r = 0; r < 4; ++r) {
      const int drow = d0 + wm + mt * 16 + quad * 4 + r;
      const size_t rowOff = ((size_t)(b * DD + drow)) * DD;
      #pragma unroll
      for (int nt = 0; nt < 4; ++nt) {
        const int ecol = e0 + wn + nt * 16 + l16;
        __builtin_nontemporal_store(accR[mt][nt][r], &out[rowOff + ecol]);
        __builtin_nontemporal_store(accI[mt][nt][r], &out[NOFF + rowOff + ecol]);
      }
    }
  }

  // ---------------- epilogue 2: mirrored tile (off-diagonal blocks only) ------------
  // out_r[b][e][d] = out_r[b][d][e];  out_i[b][e][d] = -out_i[b][d][e].
  // Per-wave transpose of its 64x64 sub-tile through LDS, in 16-row slabs:
  // slab buffer layout [col 0..63][row 0..15], stride 16 (f32x4-aligned).
  if (ti != tj) {
    float* tbR = (float*)(smem + wid * 8192);  // 4 KB per wave
    float* tbI = tbR + 1024;                   // 4 KB per wave
    #pragma unroll
    for (int mt = 0; mt < 4; ++mt) {
      __syncthreads();  // slab buffer reuse (also guards staging-LDS readers at mt=0)
      #pragma unroll
      for (int nt = 0; nt < 4; ++nt) {
        const int col = nt * 16 + l16;
        *(f32x4*)&tbR[col * 16 + quad * 4] = accR[mt][nt];
        const f32x4 vi = accI[mt][nt];
        *(f32x4*)&tbI[col * 16 + quad * 4] = (f32x4){-vi[0], -vi[1], -vi[2], -vi[3]};
      }
      __syncthreads();
      // lane -> transposed row e0+wn+lane; writes 16 floats (one aligned 64B chunk)
      const size_t trOff = ((size_t)(b * DD + e0 + wn + lane)) * DD
                         + (size_t)(d0 + wm + mt * 16);
      #pragma unroll
      for (int j = 0; j < 4; ++j) {
        const f32x4 vr = *(const f32x4*)&tbR[lane * 16 + j * 4];
        const f32x4 vi = *(const f32x4*)&tbI[lane * 16 + j * 4];
        __builtin_nontemporal_store(vr, (f32x4*)&out[trOff + j * 4]);
        __builtin_nontemporal_store(vi, (f32x4*)&out[NOFF + trOff + j * 4]);
      }
    }
  }
}

extern "C" void kernel_launch(void* const* d_in, const int* in_sizes, int n_in,
                              void* d_out, int out_size, void* d_ws, size_t ws_size,
                              hipStream_t stream) {
  const float* re = (const float*)d_in[0];
  const float* im = (const float*)d_in[1];
  const float* wt = (const float*)d_in[2];
  float* out = (float*)d_out;
  ComplexMixture_54838142435828_kernel<<<dim3(640), dim3(256), 0, stream>>>(re, im, wt, out);
}

// Round 2
// 208.332 us; speedup vs baseline: 1.6275x; 1.6275x over previous
//
#include <hip/hip_runtime.h>
#include <cstdint>
#include <cstddef>

// Problem constants (from reference setup_inputs)
#define BB 64
#define TT 256
#define DD 512
#define BK 32
#define TILEM 128

typedef short bf16x8 __attribute__((ext_vector_type(8)));  // 8 bf16 in 4 VGPRs
typedef float f32x4  __attribute__((ext_vector_type(4)));  // MFMA acc
typedef int   i32x4  __attribute__((ext_vector_type(4)));  // 16B LDS store

// fp32 -> bf16, round-half-up (1 add + shift; bias 2^-17, irrelevant vs threshold)
static __device__ __forceinline__ unsigned short f2bf(float x) {
  unsigned u = __builtin_bit_cast(unsigned, x) + 0x8000u;
  return (unsigned short)(u >> 16);
}

// SYMMETRY: out_r[b] symmetric, out_i[b] antisymmetric -> compute only the 10
// lower-triangular 128x128 tiles per batch (vs 16): -37.5% MFMA + staged reads.
// Off-diagonal blocks also write the mirrored tile (out_r copied, out_i negated)
// through a WAVE-PRIVATE LDS transpose (no barriers needed).
// DIAGONAL tiles: A-side and B-side load identical global data (d0==e0), so the
// global loads are merged (one load, scaled + raw copies) -> those blocks stage
// half the bytes.
//
// Round-1 lesson (counters): __syncthreads() AFTER global stores forces
// s_waitcnt vmcnt(0) drains (8x per block -> +130us stall), and nontemporal
// stores broke L2 write-combining (WRITE_SIZE 131->231 MB). This version has
// exactly ONE post-k-loop barrier, placed BEFORE any global store, and uses
// plain stores only.
__global__ __launch_bounds__(256, 2)
void ComplexMixture_54838142435828_kernel(const float* __restrict__ re,
                                          const float* __restrict__ im,
                                          const float* __restrict__ wt,
                                          float* __restrict__ out) {
  // Unified LDS: staging arrays during k-loop; first 32 KB reused by the
  // per-wave epilogue transpose (8 KB per wave, wave-private).
  __shared__ __attribute__((aligned(16))) char smem[33792];
  unsigned short* sAr = (unsigned short*)(smem);           // w*R, rows d   (8 KB)
  unsigned short* sAi = (unsigned short*)(smem + 8192);    // w*I, rows d   (8 KB)
  unsigned short* sBr = (unsigned short*)(smem + 16384);   // R, cols e     (8 KB)
  unsigned short* sBi = (unsigned short*)(smem + 24576);   // I, cols e     (8 KB)
  float*          sw  = (float*)(smem + 32768);            // weights       (1 KB)

  const int tid = threadIdx.x;

  // ---- XCD-cluster swizzle + triangular tile map ----
  const int L = blockIdx.x;        // 0..639
  const int c = L & 7;             // XCD (round-robin dispatch by linear id)
  const int s = L >> 3;            // 0..79 within XCD
  const int b  = c * 8 + s / 10;   // 8 batches per XCD, 10 tiles each
  const int t  = s % 10;           // triangular tile id 0..9
  const int ti = (t >= 6) ? 3 : (t >= 3) ? 2 : (t >= 1) ? 1 : 0;
  const int tj = t - ((ti * (ti + 1)) >> 1);   // ti >= tj always
  const int d0 = ti * TILEM;       // output row tile
  const int e0 = tj * TILEM;       // output col tile

  sw[tid] = wt[b * TT + tid];  // T == blockDim.x == 256; synced by loop-top barrier

  const int lane = tid & 63;
  const int wid  = tid >> 6;
  const int wm = (wid >> 1) * 64;  // wave row offset in tile
  const int wn = (wid & 1) * 64;   // wave col offset in tile
  const int quad = lane >> 4;      // selects k-octet (chunk)
  const int l16  = lane & 15;

  f32x4 accR[4][4], accI[4][4];
  #pragma unroll
  for (int mt = 0; mt < 4; ++mt)
    #pragma unroll
    for (int nt = 0; nt < 4; ++nt) {
      accR[mt][nt] = (f32x4){0.f, 0.f, 0.f, 0.f};
      accI[mt][nt] = (f32x4){0.f, 0.f, 0.f, 0.f};
    }

  // Staging role: thread covers column (d0|e0)+sd, k-range [kh*16, kh*16+16)
  const int sd = tid & 127;
  const int kh = tid >> 7;
  const bool diag = (ti == tj);

  for (int kt = 0; kt < TT; kt += BK) {
    __syncthreads();  // protect LDS from previous iteration's readers (and sw init)

    // ---------------- stage global -> LDS (transpose to k-contiguous, bf16) ---------
    const int kb = kt + kh * 16;  // global t base for this thread (within [0,T))
    const size_t rowBase = ((size_t)(b * TT + kb)) * DD;

    if (diag) {
      // A and B read the SAME global data: load once, write scaled + raw copies.
      const float* pr = re + rowBase + d0 + sd;
      const float* pi = im + rowBase + d0 + sd;
      #pragma unroll
      for (int cc = 0; cc < 2; ++cc) {
        union { unsigned short h[8]; i32x4 q; } ar, ai, br, bi;
        #pragma unroll
        for (int j = 0; j < 8; ++j) {
          const int k = cc * 8 + j;
          const float wv = sw[kb + k];
          const float rv = pr[(size_t)k * DD];
          const float iv = pi[(size_t)k * DD];
          ar.h[j] = f2bf(rv * wv);
          ai.h[j] = f2bf(iv * wv);
          br.h[j] = f2bf(rv);
          bi.h[j] = f2bf(iv);
        }
        const int off = ((kh * 2 + cc) * 128 + sd) * 8;
        *(i32x4*)&sAr[off] = ar.q;
        *(i32x4*)&sAi[off] = ai.q;
        *(i32x4*)&sBr[off] = br.q;
        *(i32x4*)&sBi[off] = bi.q;
      }
    } else {
      {  // A-side tiles (w-scaled), columns d0..d0+127
        const float* pr = re + rowBase + d0 + sd;
        const float* pi = im + rowBase + d0 + sd;
        #pragma unroll
        for (int cc = 0; cc < 2; ++cc) {
          union { unsigned short h[8]; i32x4 q; } ur, ui;
          #pragma unroll
          for (int j = 0; j < 8; ++j) {
            const int k = cc * 8 + j;
            const float wv = sw[kb + k];
            ur.h[j] = f2bf(pr[(size_t)k * DD] * wv);
            ui.h[j] = f2bf(pi[(size_t)k * DD] * wv);
          }
          const int off = ((kh * 2 + cc) * 128 + sd) * 8;
          *(i32x4*)&sAr[off] = ur.q;
          *(i32x4*)&sAi[off] = ui.q;
        }
      }
      {  // B-side tiles (unscaled), columns e0..e0+127
        const float* qr = re + rowBase + e0 + sd;
        const float* qi = im + rowBase + e0 + sd;
        #pragma unroll
        for (int cc = 0; cc < 2; ++cc) {
          union { unsigned short h[8]; i32x4 q; } ur, ui;
          #pragma unroll
          for (int j = 0; j < 8; ++j) {
            const int k = cc * 8 + j;
            ur.h[j] = f2bf(qr[(size_t)k * DD]);
            ui.h[j] = f2bf(qi[(size_t)k * DD]);
          }
          const int off = ((kh * 2 + cc) * 128 + sd) * 8;
          *(i32x4*)&sBr[off] = ur.q;
          *(i32x4*)&sBi[off] = ui.q;
        }
      }
    }
    __syncthreads();

    // ---------------- compute: one MFMA K=32 step ----------------------------------
    // A frag: A[m=lane&15][k=quad*8+j]  (m89-verified); B symmetric.
    bf16x8 aR[4], aI[4], bR[4], bI[4];
    #pragma unroll
    for (int tt = 0; tt < 4; ++tt) {
      const int offA = (quad * 128 + wm + tt * 16 + l16) * 8;
      const int offB = (quad * 128 + wn + tt * 16 + l16) * 8;
      aR[tt] = *(const bf16x8*)&sAr[offA];
      aI[tt] = *(const bf16x8*)&sAi[offA];
      bR[tt] = *(const bf16x8*)&sBr[offB];
      bI[tt] = *(const bf16x8*)&sBi[offB];
    }
    #pragma unroll
    for (int mt = 0; mt < 4; ++mt) {
      const bf16x8 aRn = aR[mt] ^ (bf16x8)((short)0x8000);  // -(w*R) via sign flip
      #pragma unroll
      for (int nt = 0; nt < 4; ++nt) {
        accR[mt][nt] = __builtin_amdgcn_mfma_f32_16x16x32_bf16(aR[mt], bR[nt], accR[mt][nt], 0, 0, 0);
        accR[mt][nt] = __builtin_amdgcn_mfma_f32_16x16x32_bf16(aI[mt], bI[nt], accR[mt][nt], 0, 0, 0);
        accI[mt][nt] = __builtin_amdgcn_mfma_f32_16x16x32_bf16(aI[mt], bR[nt], accI[mt][nt], 0, 0, 0);
        accI[mt][nt] = __builtin_amdgcn_mfma_f32_16x16x32_bf16(aRn,    bI[nt], accI[mt][nt], 0, 0, 0);
      }
    }
  }

  // ONE barrier: last k-iteration's staging-LDS readers must finish before the
  // slab region (aliasing sAr..sBi) is reused. Placed BEFORE any global store,
  // so no store stream ever hits a vmcnt(0) drain.
  __syncthreads();

  // ---------------- epilogue 1: direct tile (C/D layout col=lane&15, row=quad*4+r) --
  const size_t NOFF = (size_t)BB * DD * DD;  // out_i offset in flat tuple output
  #pragma unroll
  for (int mt = 0; mt < 4; ++mt) {
    #pragma unroll
    for (int r = 0; r < 4; ++r) {
      const int drow = d0 + wm + mt * 16 + quad * 4 + r;
      const size_t rowOff = ((size_t)(b * DD + drow)) * DD;
      #pragma unroll
      for (int nt = 0; nt < 4; ++nt) {
        const int ecol = e0 + wn + nt * 16 + l16;
        out[rowOff + ecol]        = accR[mt][nt][r];
        out[NOFF + rowOff + ecol] = accI[mt][nt][r];
      }
    }
  }

  // ---------------- epilogue 2: mirrored tile (off-diagonal blocks only) ------------
  // out_r[b][e][d] = out_r[b][d][e];  out_i[b][e][d] = -out_i[b][d][e].
  // WAVE-PRIVATE 8 KB slab (no barriers; same-wave DS ordering via lgkmcnt).
  // Slab layout [row 0..15][col 0..63] f32: writes scalar 4-way-conflicted
  // (cheap), reads scalar 2-way (free), global stores coalesced 16B.
  if (ti != tj) {
    float* tbR = (float*)(smem + wid * 8192);  // 4 KB per wave
    float* tbI = tbR + 1024;                   // 4 KB per wave
    #pragma unroll
    for (int mt = 0; mt < 4; ++mt) {
      // write slab: element (row=quad*4+r within slab, col=nt*16+l16)
      #pragma unroll
      for (int nt = 0; nt < 4; ++nt) {
        #pragma unroll
        for (int r = 0; r < 4; ++r) {
          const int a = (quad * 4 + r) * 64 + nt * 16 + l16;
          tbR[a] = accR[mt][nt][r];
          tbI[a] = -accI[mt][nt][r];
        }
      }
      // read transposed: lane owns mirror row e0+wn+lane; its 16 d-values for
      // this slab are rows 0..15 at col=lane.
      const size_t trOff = ((size_t)(b * DD + e0 + wn + lane)) * DD
                         + (size_t)(d0 + wm + mt * 16);
      #pragma unroll
      for (int j = 0; j < 4; ++j) {
        f32x4 vr, vi;
        #pragma unroll
        for (int q = 0; q < 4; ++q) {
          vr[q] = tbR[(j * 4 + q) * 64 + lane];
          vi[q] = tbI[(j * 4 + q) * 64 + lane];
        }
        *(f32x4*)&out[trOff + j * 4]        = vr;
        *(f32x4*)&out[NOFF + trOff + j * 4] = vi;
      }
    }
  }
}

extern "C" void kernel_launch(void* const* d_in, const int* in_sizes, int n_in,
                              void* d_out, int out_size, void* d_ws, size_t ws_size,
                              hipStream_t stream) {
  const float* re = (const float*)d_in[0];
  const float* im = (const float*)d_in[1];
  const float* wt = (const float*)d_in[2];
  float* out = (float*)d_out;
  ComplexMixture_54838142435828_kernel<<<dim3(640), dim3(256), 0, stream>>>(re, im, wt, out);
}